// Round 8
// baseline (319.731 us; speedup 1.0000x reference)
//
#include <hip/hip_runtime.h>

#define B_ 64
#define C_ 256
#define TV_ 1600
#define V_ 25
#define H_ 8

typedef __attribute__((ext_vector_type(2))) int   intx2;
typedef __attribute__((ext_vector_type(4))) int   intx4;
typedef __attribute__((ext_vector_type(4))) float floatx4;
typedef __attribute__((ext_vector_type(8))) short short8;

__device__ __forceinline__ unsigned short f2bf(float f) {
    union { float f; unsigned u; } c; c.f = f;
    unsigned u = c.u;
    u += 0x7fffu + ((u >> 16) & 1u);   // RNE (no NaN inputs in this problem)
    return (unsigned short)(u >> 16);
}
__device__ __forceinline__ float bf2f(unsigned short s) {
    union { unsigned u; float f; } c; c.u = ((unsigned)s) << 16;
    return c.f;
}
__device__ __forceinline__ int pk_bf2(float a, float b) {
    return (int)((unsigned)f2bf(a) | ((unsigned)f2bf(b) << 16));
}

// ---------------- k_pre: fused {k0 Qtilde | kz zero+cast | k1 transpose} ----------------
// blocks [0,512):    Qt[b,h,25,256] = temp/sqrt(32)*log2e * (xc @ qw_h^T) @ kw_h  (k0 first:
//                    long serial blocks overlap under k1's memory span — r5 verified +40%)
// blocks [512,1104): zero OA+L (528 blocks); cast vw/pw -> bf16 (64 blocks)
// blocks [1104,2704): x_patch (B,C,1600) fp32 -> XF frag-major bf16, BARRIER-FREE:
//                    each thread builds its 16-B chunk from 8 coalesced dword loads
//                    (r6-verified form: 83 µs; r4/r7 showed compiler sinks wider preloads).
__global__ __launch_bounds__(256) void k_pre(
        const float* __restrict__ xp, unsigned short* __restrict__ XF,
        const float* __restrict__ xcls, const float* __restrict__ qw,
        const float* __restrict__ kw, const float* __restrict__ temp,
        unsigned short* __restrict__ QT,
        float* __restrict__ zbase,
        const float* __restrict__ vw, const float* __restrict__ pw,
        unsigned short* __restrict__ VWB, unsigned short* __restrict__ PWB) {
    __shared__ float smem[9152];     // used by k0 branch only (36,608 B -> 4 blocks/CU)
    const int blk = blockIdx.x;
    const int t = threadIdx.x;

    if (blk >= 1104) {
        // ---- k1: XF chunk = (b*50 + nt)*1024 + cg*32 + n32; chunk payload = 8
        // consecutive-c bf16 (c = cg*8..+7) for one n = exactly k2's MFMA frag order.
        // Per load instr: whole wave shares (cg,k) -> reads xp[row][n0..n0+63] = 256 B
        // contiguous. Per store instr: two 512-B contiguous segments. Zero barriers.
        const int blkk = blk - 1104;
        const int b = blkk / 25, nb = blkk - b * 25;
        const int n0 = nb * 64;
        const int n = t & 63, cq = t >> 6;
        const float* xb = xp + (size_t)b * C_ * TV_ + n0 + n;
        const size_t cb0 = (size_t)(b * 50 + nb * 2 + (n >> 5)) * 1024 + (n & 31);
        #pragma unroll 2
        for (int j4 = 0; j4 < 8; j4++) {
            const int cg = cq * 8 + j4;
            const float* src = xb + (size_t)(cg * 8) * TV_;
            float f[8];
            #pragma unroll
            for (int k = 0; k < 8; k++) f[k] = src[(size_t)k * TV_];
            intx4 w;
            w[0] = pk_bf2(f[0], f[1]);
            w[1] = pk_bf2(f[2], f[3]);
            w[2] = pk_bf2(f[4], f[5]);
            w[3] = pk_bf2(f[6], f[7]);
            *(intx4*)(XF + (cb0 + (size_t)cg * 32) * 8) = w;
        }
    } else if (blk < 512) {
        // ---- k0: xq in LDS for phases 1-2; kws ALIASES xq for phase 3 (xq dead by then).
        // kw slice prefetched into regs during phase 2, spilled to LDS after the barrier.
        float* xq  = smem;            // [q][c] stride 260 (26,000 B)
        float* kws = smem;            // [d][c] stride 260 (33,280 B), aliases xq
        float* qh  = smem + 8320;     // [q][d] stride 33  (3,300 B)
        const int b = blk >> 3, h = blk & 7;
        {
            const float* src = xcls + ((size_t)(b * C_ + t)) * V_;
            #pragma unroll
            for (int q = 0; q < V_; q++) xq[q * 260 + t] = src[q];
        }
        __syncthreads();
        // prefetch this thread's kw slice (row h*32 + t>>3, cols (t&7)*32..+31)
        floatx4 kreg[8];
        {
            const float* krow = kw + (size_t)(h * 32 + (t >> 3)) * C_ + (t & 7) * 32;
            #pragma unroll
            for (int j = 0; j < 8; j++) kreg[j] = *(const floatx4*)(krow + 4 * j);
        }
        for (int idx = t; idx < 800; idx += 256) {
            const int q = idx >> 5, d = idx & 31;
            const float* qwr = qw + (size_t)(h * 32 + d) * C_;
            float acc = 0.f;
            #pragma unroll 4
            for (int c4 = 0; c4 < 64; c4++) {
                const floatx4 a = *(const floatx4*)(qwr + 4 * c4);
                const floatx4 x = *(const floatx4*)&xq[q * 260 + 4 * c4];
                acc += a[0] * x[0] + a[1] * x[1] + a[2] * x[2] + a[3] * x[3];
            }
            qh[q * 33 + d] = acc;
        }
        __syncthreads();   // qh complete; xq dead
        {
            float* kdst = kws + (t >> 3) * 260 + (t & 7) * 32;
            #pragma unroll
            for (int j = 0; j < 8; j++) *(floatx4*)(kdst + 4 * j) = kreg[j];
        }
        __syncthreads();   // kws ready
        const float scale = temp[h] * 0.17677669529663689f * 1.4426950408889634f;
        const int qp = t & 31, cg = t >> 5;
        const int c0 = cg * 32;
        if (qp < 25) {
            floatx4 a4[8];
            #pragma unroll
            for (int j = 0; j < 8; j++) a4[j] = (floatx4){0.f, 0.f, 0.f, 0.f};
            for (int d = 0; d < 32; d++) {
                const float a = qh[qp * 33 + d];   // LDS same-addr broadcast in cg-group
                #pragma unroll
                for (int j4 = 0; j4 < 8; j4++) {
                    const floatx4 k4 = *(const floatx4*)&kws[d * 260 + c0 + 4 * j4];
                    a4[j4][0] += a * k4[0]; a4[j4][1] += a * k4[1];
                    a4[j4][2] += a * k4[2]; a4[j4][3] += a * k4[3];
                }
            }
            unsigned short* dst = QT + ((size_t)((b * H_ + h) * 25 + qp)) * C_ + c0;
            #pragma unroll
            for (int j8 = 0; j8 < 4; j8++) {
                intx4 w;
                w[0] = pk_bf2(scale * a4[j8 * 2][0],     scale * a4[j8 * 2][1]);
                w[1] = pk_bf2(scale * a4[j8 * 2][2],     scale * a4[j8 * 2][3]);
                w[2] = pk_bf2(scale * a4[j8 * 2 + 1][0], scale * a4[j8 * 2 + 1][1]);
                w[3] = pk_bf2(scale * a4[j8 * 2 + 1][2], scale * a4[j8 * 2 + 1][3]);
                *(intx4*)(dst + j8 * 8) = w;
            }
        }
    } else {
        const int blk3 = blk - 512;
        if (blk3 < 528) {
            const int i = blk3 * 256 + t;   // 528*256 float4 = 2,162,688 B (OA + L)
            ((floatx4*)zbase)[i] = (floatx4){0.f, 0.f, 0.f, 0.f};
        } else {
            const int g = (blk3 - 528) * 256 + t;  // 16384 float4
            const floatx4 v = ((const floatx4*)vw)[g];
            const floatx4 p = ((const floatx4*)pw)[g];
            ((intx2*)VWB)[g] = (intx2){pk_bf2(v[0], v[1]), pk_bf2(v[2], v[3])};
            ((intx2*)PWB)[g] = (intx2){pk_bf2(p[0], p[1]), pk_bf2(p[2], p[3])};
        }
    }
}

// ---------------- K2: block=(b, s of 64 n-rows), 8 waves = 8 heads, X shared via LDS ----
// Grid 640 -> 1600 (2 tiles/block, s in 0..24): 12,800 waves = 3.1 machine-fills (was
// 1.25) — amortizes ramp/tail and gives co-resident blocks to hide the per-tile
// latency chain. Double-buffered Xs, one barrier per tile, unchanged per-tile code.
__global__ __launch_bounds__(512, 2) void k2_attn(
        const unsigned short* __restrict__ XF, const unsigned short* __restrict__ QT,
        const unsigned short* __restrict__ VWB, float* __restrict__ OA,
        float* __restrict__ L) {
    __shared__ unsigned short Xs[2][8192];     // 2 x 16 KB, frag-major
    __shared__ unsigned short Ps[8][32 * 40];  // per-head P  [q][n], pad 40 (80 B rows keep
    __shared__ unsigned short Vs[8][32 * 40];  // ds_read_b128 16B-aligned; pad 36 would not)

    const int blk = blockIdx.x;
    const int b = blk & 63, s = blk >> 6;      // s in 0..24
    const int tid = threadIdx.x;
    const int h = tid >> 6;                    // wave == head
    const int lane = tid & 63;
    const int quad = lane >> 4, l16 = lane & 15;

    // Q~ A-frags (rows >=25 read adjacent data / pad: finite garbage, discarded)
    short8 qf[2][8];
    {
        const unsigned short* qb = QT + (size_t)(b * H_ + h) * 25 * C_;
        #pragma unroll
        for (int mt = 0; mt < 2; mt++)
            #pragma unroll
            for (int ks = 0; ks < 8; ks++)
                qf[mt][ks] = *(const short8*)(qb + (mt * 16 + l16) * C_ + ks * 32 + quad * 8);
    }
    // v_w B-frags for this head's 32 d-columns
    short8 vwf[2][8];
    #pragma unroll
    for (int dt = 0; dt < 2; dt++)
        #pragma unroll
        for (int ks = 0; ks < 8; ks++)
            vwf[dt][ks] = *(const short8*)(VWB + (size_t)(h * 32 + dt * 16 + l16) * C_ + ks * 32 + quad * 8);

    floatx4 oc[2][2];                           // [mt][dt]
    #pragma unroll
    for (int mt = 0; mt < 2; mt++)
        #pragma unroll
        for (int dt = 0; dt < 2; dt++) oc[mt][dt] = (floatx4){0.f, 0.f, 0.f, 0.f};
    float lsum[2][4];
    #pragma unroll
    for (int mt = 0; mt < 2; mt++)
        #pragma unroll
        for (int r = 0; r < 4; r++) lsum[mt][r] = 0.f;

    const unsigned short* xf_base = XF + (size_t)(b * 50 + s * 2) * 1024 * 8;
    intx4 px0 = *(const intx4*)(xf_base + (size_t)(tid * 2 + 0) * 8);
    intx4 px1 = *(const intx4*)(xf_base + (size_t)(tid * 2 + 1) * 8);
    *(intx4*)&Xs[0][(tid * 2 + 0) * 8] = px0;   // prologue: stage tile 0
    *(intx4*)&Xs[0][(tid * 2 + 1) * 8] = px1;
    __syncthreads();

    for (int ti = 0; ti < 2; ti++) {
        const int cur = ti & 1;
        if (ti < 1) {   // issue next tile's loads now; waited only at the ds_write below
            const unsigned short* nxt = xf_base + (size_t)(ti + 1) * 1024 * 8;
            px0 = *(const intx4*)(nxt + (size_t)(tid * 2 + 0) * 8);
            px1 = *(const intx4*)(nxt + (size_t)(tid * 2 + 1) * 8);
        }
        const unsigned short* xsc = Xs[cur];
        floatx4 sc[2][2], va[2][2];            // sc[mt][g], va[g][dt]
        #pragma unroll
        for (int i = 0; i < 2; i++)
            #pragma unroll
            for (int j = 0; j < 2; j++) {
                sc[i][j] = (floatx4){0.f, 0.f, 0.f, 0.f};
                va[i][j] = (floatx4){0.f, 0.f, 0.f, 0.f};
            }
        #pragma unroll
        for (int ks = 0; ks < 8; ks++) {
            const short8 xf0 = *(const short8*)&xsc[(((ks * 4 + quad) * 32) + l16) * 8];
            const short8 xf1 = *(const short8*)&xsc[(((ks * 4 + quad) * 32) + 16 + l16) * 8];
            sc[0][0] = __builtin_amdgcn_mfma_f32_16x16x32_bf16(qf[0][ks], xf0, sc[0][0], 0, 0, 0);
            sc[0][1] = __builtin_amdgcn_mfma_f32_16x16x32_bf16(qf[0][ks], xf1, sc[0][1], 0, 0, 0);
            sc[1][0] = __builtin_amdgcn_mfma_f32_16x16x32_bf16(qf[1][ks], xf0, sc[1][0], 0, 0, 0);
            sc[1][1] = __builtin_amdgcn_mfma_f32_16x16x32_bf16(qf[1][ks], xf1, sc[1][1], 0, 0, 0);
            va[0][0] = __builtin_amdgcn_mfma_f32_16x16x32_bf16(xf0, vwf[0][ks], va[0][0], 0, 0, 0);
            va[0][1] = __builtin_amdgcn_mfma_f32_16x16x32_bf16(xf0, vwf[1][ks], va[0][1], 0, 0, 0);
            va[1][0] = __builtin_amdgcn_mfma_f32_16x16x32_bf16(xf1, vwf[0][ks], va[1][0], 0, 0, 0);
            va[1][1] = __builtin_amdgcn_mfma_f32_16x16x32_bf16(xf1, vwf[1][ks], va[1][1], 0, 0, 0);
        }
        // P = exp2(S) -> wave-private LDS; V^T -> wave-private LDS (in-order DS, no barrier)
        #pragma unroll
        for (int mt = 0; mt < 2; mt++)
            #pragma unroll
            for (int g = 0; g < 2; g++)
                #pragma unroll
                for (int r = 0; r < 4; r++) {
                    const float p = __builtin_amdgcn_exp2f(sc[mt][g][r]);
                    lsum[mt][r] += p;
                    Ps[h][(mt * 16 + quad * 4 + r) * 40 + g * 16 + l16] = f2bf(p);
                }
        #pragma unroll
        for (int g = 0; g < 2; g++)
            #pragma unroll
            for (int dt = 0; dt < 2; dt++)
                *(intx2*)&Vs[h][(dt * 16 + l16) * 40 + g * 16 + quad * 4] =
                    (intx2){pk_bf2(va[g][dt][0], va[g][dt][1]),
                            pk_bf2(va[g][dt][2], va[g][dt][3])};
        // PV for this tile (K = 32 n-rows)
        #pragma unroll
        for (int mt = 0; mt < 2; mt++) {
            const short8 pa = *(const short8*)&Ps[h][(mt * 16 + l16) * 40 + quad * 8];
            #pragma unroll
            for (int dt = 0; dt < 2; dt++) {
                const short8 vb = *(const short8*)&Vs[h][(dt * 16 + l16) * 40 + quad * 8];
                oc[mt][dt] = __builtin_amdgcn_mfma_f32_16x16x32_bf16(pa, vb, oc[mt][dt], 0, 0, 0);
            }
        }
        if (ti < 1) {   // stage tile ti+1 into the other buffer
            *(intx4*)&Xs[cur ^ 1][(tid * 2 + 0) * 8] = px0;
            *(intx4*)&Xs[cur ^ 1][(tid * 2 + 1) * 8] = px1;
        }
        __syncthreads();   // one barrier per tile: publishes Xs[cur^1], retires reads of Xs[cur]
    }
    // reduce lsum over the 16 columns (l16) of each quad
    #pragma unroll
    for (int mt = 0; mt < 2; mt++)
        #pragma unroll
        for (int r = 0; r < 4; r++) {
            float v = lsum[mt][r];
            #pragma unroll
            for (int off = 1; off < 16; off <<= 1) v += __shfl_xor(v, off, 64);
            lsum[mt][r] = v;
        }
    const size_t bh = (size_t)(b * H_ + h);
    if (l16 == 0) {
        #pragma unroll
        for (int mt = 0; mt < 2; mt++)
            #pragma unroll
            for (int r = 0; r < 4; r++) {
                const int q = mt * 16 + quad * 4 + r;
                if (q < 25) atomicAdd(&L[bh * 32 + q], lsum[mt][r]);
            }
    }
    #pragma unroll
    for (int mt = 0; mt < 2; mt++)
        #pragma unroll
        for (int dt = 0; dt < 2; dt++)
            #pragma unroll
            for (int r = 0; r < 4; r++) {
                const int q = mt * 16 + quad * 4 + r;
                if (q < 25)
                    atomicAdd(&OA[bh * 1024 + q * 32 + dt * 16 + l16], oc[mt][dt][r]);
            }
}

// ---------------- K3 (MFMA): y[b,i,q] = pb[i] + sum_j pw[i,j] * OAnorm[b,q,j] ----------
__global__ __launch_bounds__(256) void k3_proj(const float* __restrict__ OA,
        const float* __restrict__ Lsum, const unsigned short* __restrict__ PWB,
        const float* __restrict__ pb, float* __restrict__ y) {
    __shared__ unsigned short OB[32 * 264];   // normalized O bf16, rows 25..31 zero
    __shared__ float rl_s[256];
    const int blk = blockIdx.x;
    const int b = blk >> 2, i0 = (blk & 3) * 64;
    const int t = threadIdx.x;
    const int wv = t >> 6, lane = t & 63;
    const int quad = lane >> 4, l16 = lane & 15;
    {
        const int h = t >> 5, q = t & 31;
        const float lv = Lsum[(size_t)(b * H_ + h) * 32 + q];
        rl_s[t] = (q < 25) ? 1.0f / lv : 0.0f;
    }
    __syncthreads();
    for (int idx = t; idx < 8192; idx += 256) {
        const int q = idx >> 8, j = idx & 255;
        const int h2 = j >> 5, d = j & 31;
        const float val = (q < 25)
            ? OA[(size_t)(b * H_ + h2) * 1024 + q * 32 + d] * rl_s[h2 * 32 + q] : 0.f;
        OB[q * 264 + j] = f2bf(val);
    }
    __syncthreads();
    floatx4 oc[2];
    oc[0] = (floatx4){0.f, 0.f, 0.f, 0.f};
    oc[1] = (floatx4){0.f, 0.f, 0.f, 0.f};
    const int i = i0 + wv * 16 + l16;
    #pragma unroll
    for (int ks = 0; ks < 8; ks++) {
        const short8 a0 = *(const short8*)&OB[l16 * 264 + ks * 32 + quad * 8];
        const short8 a1 = *(const short8*)&OB[(16 + l16) * 264 + ks * 32 + quad * 8];
        const short8 bv = *(const short8*)(PWB + (size_t)i * C_ + ks * 32 + quad * 8);
        oc[0] = __builtin_amdgcn_mfma_f32_16x16x32_bf16(a0, bv, oc[0], 0, 0, 0);
        oc[1] = __builtin_amdgcn_mfma_f32_16x16x32_bf16(a1, bv, oc[1], 0, 0, 0);
    }
    const float bias = pb[i];
    #pragma unroll
    for (int mt = 0; mt < 2; mt++)
        #pragma unroll
        for (int r = 0; r < 4; r++) {
            const int q = mt * 16 + quad * 4 + r;
            if (q < 25) y[(size_t)b * 6400 + i * 25 + q] = oc[mt][r] + bias;
        }
}

extern "C" void kernel_launch(void* const* d_in, const int* in_sizes, int n_in,
                              void* d_out, int out_size, void* d_ws, size_t ws_size,
                              hipStream_t stream) {
    const float* xcls = (const float*)d_in[0];
    const float* xp   = (const float*)d_in[1];
    const float* qw   = (const float*)d_in[2];
    const float* kw   = (const float*)d_in[3];
    const float* vw   = (const float*)d_in[4];
    const float* temp = (const float*)d_in[5];
    const float* pw   = (const float*)d_in[6];
    const float* pb   = (const float*)d_in[7];
    float* y = (float*)d_out;

    // ws: XF 52,428,800 | QT 6,553,600+8,192 pad | OA 2,097,152 | L 65,536 | VWB 131,072 | PWB 131,072
    if (ws_size < (size_t)61415424) return;
    char* ws = (char*)d_ws;
    unsigned short* XF  = (unsigned short*)ws;
    unsigned short* QT  = (unsigned short*)(ws + 52428800);
    float*          OA  = (float*)(ws + 58990592);
    float*          L   = (float*)(ws + 61087744);
    unsigned short* VWB = (unsigned short*)(ws + 61153280);
    unsigned short* PWB = (unsigned short*)(ws + 61284352);

    hipLaunchKernelGGL(k_pre,   dim3(2704), dim3(256), 0, stream,
                       xp, XF, xcls, qw, kw, temp, QT, OA, vw, pw, VWB, PWB);
    hipLaunchKernelGGL(k2_attn, dim3(1600), dim3(512), 0, stream, XF, QT, VWB, OA, L);
    hipLaunchKernelGGL(k3_proj, dim3(256),  dim3(256), 0, stream, OA, L, PWB, pb, y);
}

// Round 9
// 267.812 us; speedup vs baseline: 1.1939x; 1.1939x over previous
//
#include <hip/hip_runtime.h>

#define B_ 64
#define C_ 256
#define TV_ 1600
#define V_ 25
#define H_ 8

typedef __attribute__((ext_vector_type(2))) int   intx2;
typedef __attribute__((ext_vector_type(4))) int   intx4;
typedef __attribute__((ext_vector_type(4))) float floatx4;
typedef __attribute__((ext_vector_type(8))) short short8;

__device__ __forceinline__ unsigned short f2bf(float f) {
    union { float f; unsigned u; } c; c.f = f;
    unsigned u = c.u;
    u += 0x7fffu + ((u >> 16) & 1u);   // RNE (no NaN inputs in this problem)
    return (unsigned short)(u >> 16);
}
__device__ __forceinline__ float bf2f(unsigned short s) {
    union { unsigned u; float f; } c; c.u = ((unsigned)s) << 16;
    return c.f;
}
__device__ __forceinline__ int pk_bf2(float a, float b) {
    return (int)((unsigned)f2bf(a) | ((unsigned)f2bf(b) << 16));
}

// ---------------- k_pre: fused {k0 Qtilde | cast | k1 transpose} ----------------
// blocks [0,512):   Qt[b,h,25,256] = temp/sqrt(32)*log2e * (xc @ qw_h^T) @ kw_h (k0 first:
//                   long serial blocks overlap under k1's memory span — r5 verified +40%)
// blocks [512,576): cast vw/pw -> bf16 (OA/L zeroing no longer needed: k2 now writes
//                   partials with plain stores, no atomic accumulation)
// blocks [576,2176): x_patch (B,C,1600) fp32 -> XF frag-major bf16, BARRIER-FREE
//                   (r6-verified form: 83 µs; r4/r7 showed compiler sinks wider preloads).
__global__ __launch_bounds__(256) void k_pre(
        const float* __restrict__ xp, unsigned short* __restrict__ XF,
        const float* __restrict__ xcls, const float* __restrict__ qw,
        const float* __restrict__ kw, const float* __restrict__ temp,
        unsigned short* __restrict__ QT,
        const float* __restrict__ vw, const float* __restrict__ pw,
        unsigned short* __restrict__ VWB, unsigned short* __restrict__ PWB) {
    __shared__ float smem[9152];     // used by k0 branch only (36,608 B -> 4 blocks/CU)
    const int blk = blockIdx.x;
    const int t = threadIdx.x;

    if (blk >= 576) {
        // ---- k1: XF chunk = (b*50 + nt)*1024 + cg*32 + n32; chunk payload = 8
        // consecutive-c bf16 (c = cg*8..+7) for one n = exactly k2's MFMA frag order.
        // Per load instr: whole wave shares (cg,k) -> reads xp[row][n0..n0+63] = 256 B
        // contiguous. Per store instr: two 512-B contiguous segments. Zero barriers.
        const int blkk = blk - 576;
        const int b = blkk / 25, nb = blkk - b * 25;
        const int n0 = nb * 64;
        const int n = t & 63, cq = t >> 6;
        const float* xb = xp + (size_t)b * C_ * TV_ + n0 + n;
        const size_t cb0 = (size_t)(b * 50 + nb * 2 + (n >> 5)) * 1024 + (n & 31);
        #pragma unroll 2
        for (int j4 = 0; j4 < 8; j4++) {
            const int cg = cq * 8 + j4;
            const float* src = xb + (size_t)(cg * 8) * TV_;
            float f[8];
            #pragma unroll
            for (int k = 0; k < 8; k++) f[k] = src[(size_t)k * TV_];
            intx4 w;
            w[0] = pk_bf2(f[0], f[1]);
            w[1] = pk_bf2(f[2], f[3]);
            w[2] = pk_bf2(f[4], f[5]);
            w[3] = pk_bf2(f[6], f[7]);
            *(intx4*)(XF + (cb0 + (size_t)cg * 32) * 8) = w;
        }
    } else if (blk < 512) {
        // ---- k0: xq in LDS for phases 1-2; kws ALIASES xq for phase 3 (xq dead by then).
        // kw slice prefetched into regs during phase 2, spilled to LDS after the barrier.
        float* xq  = smem;            // [q][c] stride 260 (26,000 B)
        float* kws = smem;            // [d][c] stride 260 (33,280 B), aliases xq
        float* qh  = smem + 8320;     // [q][d] stride 33  (3,300 B)
        const int b = blk >> 3, h = blk & 7;
        {
            const float* src = xcls + ((size_t)(b * C_ + t)) * V_;
            #pragma unroll
            for (int q = 0; q < V_; q++) xq[q * 260 + t] = src[q];
        }
        __syncthreads();
        // prefetch this thread's kw slice (row h*32 + t>>3, cols (t&7)*32..+31)
        floatx4 kreg[8];
        {
            const float* krow = kw + (size_t)(h * 32 + (t >> 3)) * C_ + (t & 7) * 32;
            #pragma unroll
            for (int j = 0; j < 8; j++) kreg[j] = *(const floatx4*)(krow + 4 * j);
        }
        for (int idx = t; idx < 800; idx += 256) {
            const int q = idx >> 5, d = idx & 31;
            const float* qwr = qw + (size_t)(h * 32 + d) * C_;
            float acc = 0.f;
            #pragma unroll 4
            for (int c4 = 0; c4 < 64; c4++) {
                const floatx4 a = *(const floatx4*)(qwr + 4 * c4);
                const floatx4 x = *(const floatx4*)&xq[q * 260 + 4 * c4];
                acc += a[0] * x[0] + a[1] * x[1] + a[2] * x[2] + a[3] * x[3];
            }
            qh[q * 33 + d] = acc;
        }
        __syncthreads();   // qh complete; xq dead
        {
            float* kdst = kws + (t >> 3) * 260 + (t & 7) * 32;
            #pragma unroll
            for (int j = 0; j < 8; j++) *(floatx4*)(kdst + 4 * j) = kreg[j];
        }
        __syncthreads();   // kws ready
        const float scale = temp[h] * 0.17677669529663689f * 1.4426950408889634f;
        const int qp = t & 31, cg = t >> 5;
        const int c0 = cg * 32;
        if (qp < 25) {
            floatx4 a4[8];
            #pragma unroll
            for (int j = 0; j < 8; j++) a4[j] = (floatx4){0.f, 0.f, 0.f, 0.f};
            for (int d = 0; d < 32; d++) {
                const float a = qh[qp * 33 + d];   // LDS same-addr broadcast in cg-group
                #pragma unroll
                for (int j4 = 0; j4 < 8; j4++) {
                    const floatx4 k4 = *(const floatx4*)&kws[d * 260 + c0 + 4 * j4];
                    a4[j4][0] += a * k4[0]; a4[j4][1] += a * k4[1];
                    a4[j4][2] += a * k4[2]; a4[j4][3] += a * k4[3];
                }
            }
            unsigned short* dst = QT + ((size_t)((b * H_ + h) * 25 + qp)) * C_ + c0;
            #pragma unroll
            for (int j8 = 0; j8 < 4; j8++) {
                intx4 w;
                w[0] = pk_bf2(scale * a4[j8 * 2][0],     scale * a4[j8 * 2][1]);
                w[1] = pk_bf2(scale * a4[j8 * 2][2],     scale * a4[j8 * 2][3]);
                w[2] = pk_bf2(scale * a4[j8 * 2 + 1][0], scale * a4[j8 * 2 + 1][1]);
                w[3] = pk_bf2(scale * a4[j8 * 2 + 1][2], scale * a4[j8 * 2 + 1][3]);
                *(intx4*)(dst + j8 * 8) = w;
            }
        }
    } else {
        const int g = (blk - 512) * 256 + t;  // 16384 float4
        const floatx4 v = ((const floatx4*)vw)[g];
        const floatx4 p = ((const floatx4*)pw)[g];
        ((intx2*)VWB)[g] = (intx2){pk_bf2(v[0], v[1]), pk_bf2(v[2], v[3])};
        ((intx2*)PWB)[g] = (intx2){pk_bf2(p[0], p[1]), pk_bf2(p[2], p[3])};
    }
}

// ---------------- K2: block=(b, s of 160 n-rows), 8 waves = 8 heads, X shared via LDS ----
// Epilogue: plain stores of per-s partials (OAP/LP) — NO device atomics. r8 showed the
// atomic epilogue write-through (4B memory-side RMW) was ~42% of k2's time.
__global__ __launch_bounds__(512, 2) void k2_attn(
        const unsigned short* __restrict__ XF, const unsigned short* __restrict__ QT,
        const unsigned short* __restrict__ VWB, float* __restrict__ OAP,
        float* __restrict__ LP) {
    __shared__ unsigned short Xs[2][8192];     // 2 x 16 KB, frag-major
    __shared__ unsigned short Ps[8][32 * 40];  // per-head P  [q][n], pad 40 (80 B rows keep
    __shared__ unsigned short Vs[8][32 * 40];  // ds_read_b128 16B-aligned; pad 36 would not)

    const int blk = blockIdx.x;
    const int b = blk & 63, s = blk >> 6;      // s in 0..9
    const int tid = threadIdx.x;
    const int h = tid >> 6;                    // wave == head
    const int lane = tid & 63;
    const int quad = lane >> 4, l16 = lane & 15;

    // Q~ A-frags (rows >=25 read adjacent data / pad: finite garbage, discarded)
    short8 qf[2][8];
    {
        const unsigned short* qb = QT + (size_t)(b * H_ + h) * 25 * C_;
        #pragma unroll
        for (int mt = 0; mt < 2; mt++)
            #pragma unroll
            for (int ks = 0; ks < 8; ks++)
                qf[mt][ks] = *(const short8*)(qb + (mt * 16 + l16) * C_ + ks * 32 + quad * 8);
    }
    // v_w B-frags for this head's 32 d-columns
    short8 vwf[2][8];
    #pragma unroll
    for (int dt = 0; dt < 2; dt++)
        #pragma unroll
        for (int ks = 0; ks < 8; ks++)
            vwf[dt][ks] = *(const short8*)(VWB + (size_t)(h * 32 + dt * 16 + l16) * C_ + ks * 32 + quad * 8);

    floatx4 oc[2][2];                           // [mt][dt]
    #pragma unroll
    for (int mt = 0; mt < 2; mt++)
        #pragma unroll
        for (int dt = 0; dt < 2; dt++) oc[mt][dt] = (floatx4){0.f, 0.f, 0.f, 0.f};
    float lsum[2][4];
    #pragma unroll
    for (int mt = 0; mt < 2; mt++)
        #pragma unroll
        for (int r = 0; r < 4; r++) lsum[mt][r] = 0.f;

    const unsigned short* xf_base = XF + (size_t)(b * 50 + s * 5) * 1024 * 8;
    intx4 px0 = *(const intx4*)(xf_base + (size_t)(tid * 2 + 0) * 8);
    intx4 px1 = *(const intx4*)(xf_base + (size_t)(tid * 2 + 1) * 8);
    *(intx4*)&Xs[0][(tid * 2 + 0) * 8] = px0;   // prologue: stage tile 0
    *(intx4*)&Xs[0][(tid * 2 + 1) * 8] = px1;
    __syncthreads();

    for (int ti = 0; ti < 5; ti++) {
        const int cur = ti & 1;
        if (ti < 4) {   // issue next tile's loads now; waited only at the ds_write below
            const unsigned short* nxt = xf_base + (size_t)(ti + 1) * 1024 * 8;
            px0 = *(const intx4*)(nxt + (size_t)(tid * 2 + 0) * 8);
            px1 = *(const intx4*)(nxt + (size_t)(tid * 2 + 1) * 8);
        }
        const unsigned short* xsc = Xs[cur];
        floatx4 sc[2][2], va[2][2];            // sc[mt][g], va[g][dt]
        #pragma unroll
        for (int i = 0; i < 2; i++)
            #pragma unroll
            for (int j = 0; j < 2; j++) {
                sc[i][j] = (floatx4){0.f, 0.f, 0.f, 0.f};
                va[i][j] = (floatx4){0.f, 0.f, 0.f, 0.f};
            }
        #pragma unroll
        for (int ks = 0; ks < 8; ks++) {
            const short8 xf0 = *(const short8*)&xsc[(((ks * 4 + quad) * 32) + l16) * 8];
            const short8 xf1 = *(const short8*)&xsc[(((ks * 4 + quad) * 32) + 16 + l16) * 8];
            sc[0][0] = __builtin_amdgcn_mfma_f32_16x16x32_bf16(qf[0][ks], xf0, sc[0][0], 0, 0, 0);
            sc[0][1] = __builtin_amdgcn_mfma_f32_16x16x32_bf16(qf[0][ks], xf1, sc[0][1], 0, 0, 0);
            sc[1][0] = __builtin_amdgcn_mfma_f32_16x16x32_bf16(qf[1][ks], xf0, sc[1][0], 0, 0, 0);
            sc[1][1] = __builtin_amdgcn_mfma_f32_16x16x32_bf16(qf[1][ks], xf1, sc[1][1], 0, 0, 0);
            va[0][0] = __builtin_amdgcn_mfma_f32_16x16x32_bf16(xf0, vwf[0][ks], va[0][0], 0, 0, 0);
            va[0][1] = __builtin_amdgcn_mfma_f32_16x16x32_bf16(xf0, vwf[1][ks], va[0][1], 0, 0, 0);
            va[1][0] = __builtin_amdgcn_mfma_f32_16x16x32_bf16(xf1, vwf[0][ks], va[1][0], 0, 0, 0);
            va[1][1] = __builtin_amdgcn_mfma_f32_16x16x32_bf16(xf1, vwf[1][ks], va[1][1], 0, 0, 0);
        }
        // P = exp2(S) -> wave-private LDS; V^T -> wave-private LDS (in-order DS, no barrier)
        #pragma unroll
        for (int mt = 0; mt < 2; mt++)
            #pragma unroll
            for (int g = 0; g < 2; g++)
                #pragma unroll
                for (int r = 0; r < 4; r++) {
                    const float p = __builtin_amdgcn_exp2f(sc[mt][g][r]);
                    lsum[mt][r] += p;
                    Ps[h][(mt * 16 + quad * 4 + r) * 40 + g * 16 + l16] = f2bf(p);
                }
        #pragma unroll
        for (int g = 0; g < 2; g++)
            #pragma unroll
            for (int dt = 0; dt < 2; dt++)
                *(intx2*)&Vs[h][(dt * 16 + l16) * 40 + g * 16 + quad * 4] =
                    (intx2){pk_bf2(va[g][dt][0], va[g][dt][1]),
                            pk_bf2(va[g][dt][2], va[g][dt][3])};
        // PV for this tile (K = 32 n-rows)
        #pragma unroll
        for (int mt = 0; mt < 2; mt++) {
            const short8 pa = *(const short8*)&Ps[h][(mt * 16 + l16) * 40 + quad * 8];
            #pragma unroll
            for (int dt = 0; dt < 2; dt++) {
                const short8 vb = *(const short8*)&Vs[h][(dt * 16 + l16) * 40 + quad * 8];
                oc[mt][dt] = __builtin_amdgcn_mfma_f32_16x16x32_bf16(pa, vb, oc[mt][dt], 0, 0, 0);
            }
        }
        if (ti < 4) {   // stage tile ti+1 into the other buffer (reads ended at barrier ti-1)
            *(intx4*)&Xs[cur ^ 1][(tid * 2 + 0) * 8] = px0;
            *(intx4*)&Xs[cur ^ 1][(tid * 2 + 1) * 8] = px1;
        }
        __syncthreads();   // one barrier per tile: publishes Xs[cur^1], retires reads of Xs[cur]
    }
    // reduce lsum over the 16 columns (l16) of each quad
    #pragma unroll
    for (int mt = 0; mt < 2; mt++)
        #pragma unroll
        for (int r = 0; r < 4; r++) {
            float v = lsum[mt][r];
            #pragma unroll
            for (int off = 1; off < 16; off <<= 1) v += __shfl_xor(v, off, 64);
            lsum[mt][r] = v;
        }
    const size_t bh = (size_t)(b * H_ + h);
    if (l16 == 0) {
        #pragma unroll
        for (int mt = 0; mt < 2; mt++)
            #pragma unroll
            for (int r = 0; r < 4; r++) {
                const int q = mt * 16 + quad * 4 + r;   // covers 0..31
                LP[bh * 320 + s * 32 + q] = lsum[mt][r];
            }
    }
    #pragma unroll
    for (int mt = 0; mt < 2; mt++)
        #pragma unroll
        for (int dt = 0; dt < 2; dt++)
            #pragma unroll
            for (int r = 0; r < 4; r++) {
                const int q = mt * 16 + quad * 4 + r;
                if (q < 25)
                    OAP[((size_t)(bh * 25 + q)) * 320 + s * 32 + dt * 16 + l16] = oc[mt][dt][r];
            }
}

// ---------------- K3 (MFMA): y[b,i,q] = pb[i] + sum_j pw[i,j] * OAnorm[b,q,j] ----------
// OB staging sums the 10 s-partials. b = blk&63 so the 4 blocks sharing b are 64 apart
// -> same XCD (64%8==0) -> partials hit the same L2.
__global__ __launch_bounds__(256) void k3_proj(const float* __restrict__ OAP,
        const float* __restrict__ LP, const unsigned short* __restrict__ PWB,
        const float* __restrict__ pb, float* __restrict__ y) {
    __shared__ unsigned short OB[32 * 264];   // normalized O bf16, rows 25..31 zero
    __shared__ float rl_s[256];
    const int blk = blockIdx.x;
    const int b = blk & 63, i0 = (blk >> 6) * 64;
    const int t = threadIdx.x;
    const int wv = t >> 6, lane = t & 63;
    const int quad = lane >> 4, l16 = lane & 15;
    {
        const int h = t >> 5, q = t & 31;
        const float* lp = LP + (size_t)(b * H_ + h) * 320 + q;
        float lv = 0.f;
        #pragma unroll
        for (int s = 0; s < 10; s++) lv += lp[s * 32];
        rl_s[t] = (q < 25) ? 1.0f / lv : 0.0f;
    }
    __syncthreads();
    for (int idx = t; idx < 8192; idx += 256) {
        const int q = idx >> 8, j = idx & 255;
        const int h2 = j >> 5, d = j & 31;
        float val = 0.f;
        if (q < 25) {
            const float* op = OAP + ((size_t)(b * H_ + h2) * 25 + q) * 320 + d;
            float acc = 0.f;
            #pragma unroll
            for (int s = 0; s < 10; s++) acc += op[s * 32];
            val = acc * rl_s[h2 * 32 + q];
        }
        OB[q * 264 + j] = f2bf(val);
    }
    __syncthreads();
    floatx4 oc[2];
    oc[0] = (floatx4){0.f, 0.f, 0.f, 0.f};
    oc[1] = (floatx4){0.f, 0.f, 0.f, 0.f};
    const int i = i0 + wv * 16 + l16;
    #pragma unroll
    for (int ks = 0; ks < 8; ks++) {
        const short8 a0 = *(const short8*)&OB[l16 * 264 + ks * 32 + quad * 8];
        const short8 a1 = *(const short8*)&OB[(16 + l16) * 264 + ks * 32 + quad * 8];
        const short8 bv = *(const short8*)(PWB + (size_t)i * C_ + ks * 32 + quad * 8);
        oc[0] = __builtin_amdgcn_mfma_f32_16x16x32_bf16(a0, bv, oc[0], 0, 0, 0);
        oc[1] = __builtin_amdgcn_mfma_f32_16x16x32_bf16(a1, bv, oc[1], 0, 0, 0);
    }
    const float bias = pb[i];
    #pragma unroll
    for (int mt = 0; mt < 2; mt++)
        #pragma unroll
        for (int r = 0; r < 4; r++) {
            const int q = mt * 16 + quad * 4 + r;
            if (q < 25) y[(size_t)b * 6400 + i * 25 + q] = oc[mt][r] + bias;
        }
}

extern "C" void kernel_launch(void* const* d_in, const int* in_sizes, int n_in,
                              void* d_out, int out_size, void* d_ws, size_t ws_size,
                              hipStream_t stream) {
    const float* xcls = (const float*)d_in[0];
    const float* xp   = (const float*)d_in[1];
    const float* qw   = (const float*)d_in[2];
    const float* kw   = (const float*)d_in[3];
    const float* vw   = (const float*)d_in[4];
    const float* temp = (const float*)d_in[5];
    const float* pw   = (const float*)d_in[6];
    const float* pb   = (const float*)d_in[7];
    float* y = (float*)d_out;

    // ws: XF 52,428,800 | QT 6,553,600+8,192 | OAP 16,384,000 | LP 655,360 | VWB | PWB
    if (ws_size < (size_t)76292096) return;
    char* ws = (char*)d_ws;
    unsigned short* XF  = (unsigned short*)ws;
    unsigned short* QT  = (unsigned short*)(ws + 52428800);
    float*          OAP = (float*)(ws + 58990592);
    float*          LP  = (float*)(ws + 75374592);
    unsigned short* VWB = (unsigned short*)(ws + 76029952);
    unsigned short* PWB = (unsigned short*)(ws + 76161024);

    hipLaunchKernelGGL(k_pre,   dim3(2176), dim3(256), 0, stream,
                       xp, XF, xcls, qw, kw, temp, QT, vw, pw, VWB, PWB);
    hipLaunchKernelGGL(k2_attn, dim3(640),  dim3(512), 0, stream, XF, QT, VWB, OAP, LP);
    hipLaunchKernelGGL(k3_proj, dim3(256),  dim3(256), 0, stream, OAP, LP, PWB, pb, y);
}